// Round 10
// baseline (262.884 us; speedup 1.0000x reference)
//
#include <hip/hip_runtime.h>

typedef __attribute__((ext_vector_type(8))) short bf16x8;   // 8 bf16 (4 VGPRs)
typedef __attribute__((ext_vector_type(4))) float f32x4;

#define ZV 72    // visual split-K: 72 * 12 * 64 = 69120
#define ZA 2     // audio  split-K:  2 * 10 * 64 = 1280

// pack two f32 -> one dword of 2 bf16 (RNE)
__device__ __forceinline__ unsigned int pk2(float a, float b) {
    unsigned int r;
    asm("v_cvt_pk_bf16_f32 %0, %1, %2" : "=v"(r) : "v"(a), "v"(b));
    return r;
}

// ---------------------------------------------------------------------------
// Fused GEMM: C[512,512] = A[512,K] * W[K,512], BOTH f32 direct from HBM.
// Tile 128x128, BK=64 (two 32-k staging phases), 256 thr = 4 waves (2x2 of
// 64x64). LDS: [row][8 units of 8 bf16], unit ^= row&7 (verified 0-conflict).
// A: reg-staged f32->bf16 (crop offset uniform per step; 4608 % 64 == 0).
// B: reg-gather 8 float2/phase from W k-major (rows oct*8..+7), pk2 pairs.
// Dispatch: XCD-chunked, n fastest -> panel-sharing blocks co-resident (L2).
// CROP=1: visual (row stride 138240, center crop); CROP=0: audio (1280).
// ---------------------------------------------------------------------------
template<int CROP>
__global__ __launch_bounds__(256, 4) void fgemm(
    const float* __restrict__ s1, const float* __restrict__ s2,
    const float* __restrict__ W, float* __restrict__ part, int ksteps)
{
    __shared__ uint4 As[1024];   // 16 KB
    __shared__ uint4 Bs[1024];   // 16 KB

    const int tid = threadIdx.x;
    const int blk = blockIdx.x;
    const int cpx = gridDim.x >> 3;
    const int lin = (blk & 7) * cpx + (blk >> 3);   // XCD-chunked
    const int z  = lin >> 4;
    const int m0 = ((lin >> 2) & 3) * 128;
    const int n0 = (lin & 3) * 128;                 // n fastest: A-panel shared
    const int k0 = z * ksteps * 64;
    part += (size_t)z * 262144;

    // ---- A staging map: thread -> (row 0..127, k-half 0/1)
    const int a_row  = tid >> 1;
    const int a_half = tid & 1;
    const int grow = m0 + a_row;
    const int ROWSTR = CROP ? 138240 : 1280;
    const float* abase = (grow < 256) ? s1 + (size_t)grow * ROWSTR
                                      : s2 + (size_t)(grow - 256) * ROWSTR;

    // ---- B staging map: thread -> (n-pair, k-oct)
    const int bcol  = 2 * (tid >> 2);      // 0..126 even
    const int b_oct = tid & 3;             // k rows oct*8..+7 per phase
    const float* bp = W + (size_t)(k0 + b_oct * 8) * 512 + n0 + bcol;

    // ---- wave / fragment map (round-8 verified)
    const int wid = tid >> 6, lane = tid & 63;
    const int l15 = lane & 15, lk = lane >> 4;
    const int wm = (wid >> 1) * 64, wn = (wid & 1) * 64;

    int ua[2][4], ub[2][4];
    #pragma unroll
    for (int kh = 0; kh < 2; ++kh) {
        #pragma unroll
        for (int mi = 0; mi < 4; ++mi) {
            const int row = wm + mi * 16 + l15;
            ua[kh][mi] = row * 8 + ((kh * 4 + lk) ^ (row & 7));
        }
        #pragma unroll
        for (int ni = 0; ni < 4; ++ni) {
            const int nn = wn + ni * 16 + l15;
            ub[kh][ni] = nn * 8 + ((kh * 4 + lk) ^ (nn & 7));
        }
    }

    f32x4 acc[4][4];
    #pragma unroll
    for (int mi = 0; mi < 4; ++mi)
        #pragma unroll
        for (int ni = 0; ni < 4; ++ni) acc[mi][ni] = f32x4{0.f, 0.f, 0.f, 0.f};

    int kc = k0;
    for (int ks = 0; ks < ksteps; ++ks) {
        // A source offset (block-uniform crop math; BK=64 window never
        // straddles a 4608 chunk since 4608 % 64 == 0 and k0 % 64 == 0)
        int aoffu;
        if (CROP) {
            const int p = kc / 4608;
            const int j = kc - p * 4608;
            const int c3 = p % 3, t9 = p / 3;
            aoffu = c3 * 46080 + t9 * 9216 + 4608 + j;
        } else {
            aoffu = kc;
        }

        // ---- stage BK=64 in two 32-k phases (16 f32 live per operand) ----
        #pragma unroll
        for (int ph = 0; ph < 2; ++ph) {
            // A: 16 consecutive f32 at k = ph*32 + a_half*16
            {
                const float* ap = abase + aoffu + ph * 32 + a_half * 16;
                const float4 f0 = *(const float4*)ap;
                const float4 f1 = *(const float4*)(ap + 4);
                const float4 f2 = *(const float4*)(ap + 8);
                const float4 f3 = *(const float4*)(ap + 12);
                const int x0 = ph * 4 + a_half * 2;      // unit index
                uint4 w0, w1;
                w0.x = pk2(f0.x, f0.y); w0.y = pk2(f0.z, f0.w);
                w0.z = pk2(f1.x, f1.y); w0.w = pk2(f1.z, f1.w);
                w1.x = pk2(f2.x, f2.y); w1.y = pk2(f2.z, f2.w);
                w1.z = pk2(f3.x, f3.y); w1.w = pk2(f3.z, f3.w);
                As[a_row * 8 + ( x0      ^ (a_row & 7))] = w0;
                As[a_row * 8 + ((x0 + 1) ^ (a_row & 7))] = w1;
            }
            // B: 8 float2 (rows oct*8..+7 of this 32-k phase), 2 cols each
            {
                const float* bq = bp + (size_t)(kc - k0 + ph * 32) * 512;
                float2 bv[8];
                #pragma unroll
                for (int r = 0; r < 8; ++r)
                    bv[r] = *(const float2*)(bq + (size_t)r * 512);
                const int u = ph * 4 + b_oct;
                uint4 p0, p1;
                p0.x = pk2(bv[0].x, bv[1].x); p0.y = pk2(bv[2].x, bv[3].x);
                p0.z = pk2(bv[4].x, bv[5].x); p0.w = pk2(bv[6].x, bv[7].x);
                p1.x = pk2(bv[0].y, bv[1].y); p1.y = pk2(bv[2].y, bv[3].y);
                p1.z = pk2(bv[4].y, bv[5].y); p1.w = pk2(bv[6].y, bv[7].y);
                Bs[(bcol)     * 8 + (u ^ ( bcol      & 7))] = p0;
                Bs[(bcol + 1) * 8 + (u ^ ((bcol + 1) & 7))] = p1;
            }
        }
        __syncthreads();

        // ---- compute: 2 k-halves x 16 MFMA per wave ----
        #pragma unroll
        for (int kh = 0; kh < 2; ++kh) {
            bf16x8 af[4], bfr[4];
            #pragma unroll
            for (int mi = 0; mi < 4; ++mi) af[mi] = __builtin_bit_cast(bf16x8, As[ua[kh][mi]]);
            #pragma unroll
            for (int ni = 0; ni < 4; ++ni) bfr[ni] = __builtin_bit_cast(bf16x8, Bs[ub[kh][ni]]);
            #pragma unroll
            for (int mi = 0; mi < 4; ++mi)
                #pragma unroll
                for (int ni = 0; ni < 4; ++ni)
                    acc[mi][ni] = __builtin_amdgcn_mfma_f32_16x16x32_bf16(af[mi], bfr[ni], acc[mi][ni], 0, 0, 0);
        }
        __syncthreads();

        kc += 64;
    }

    // ---- epilogue: fp32 partials. C/D: col = lane&15, row = (lane>>4)*4+r
    #pragma unroll
    for (int mi = 0; mi < 4; ++mi)
        #pragma unroll
        for (int ni = 0; ni < 4; ++ni) {
            const int col = n0 + wn + ni * 16 + l15;
            #pragma unroll
            for (int r = 0; r < 4; ++r) {
                const int row = m0 + wm + mi * 16 + lk * 4 + r;
                part[(size_t)row * 512 + col] = acc[mi][ni][r];
            }
        }
}

// ---------- reduce split-K partials + row L2 normalization ----------
__global__ __launch_bounds__(256) void norm_kernel(
    const float* __restrict__ partA, const float* __restrict__ partV,
    float* __restrict__ Aout, float* __restrict__ Vout, int nzV)
{
    const int row = blockIdx.x;          // 0..1023
    const int tid = threadIdx.x;
    const bool isV = row >= 512;
    const int r = isV ? (row - 512) : row;
    const int c0 = tid, c1 = tid + 256;

    float v0 = 0.f, v1 = 0.f;
    if (isV) {
        for (int zz = 0; zz < nzV; ++zz) {
            const float* p = partV + (size_t)zz * 262144 + (size_t)r * 512;
            v0 += p[c0]; v1 += p[c1];
        }
    } else {
        #pragma unroll
        for (int zz = 0; zz < ZA; ++zz) {
            const float* p = partA + (size_t)zz * 262144 + (size_t)r * 512;
            v0 += p[c0]; v1 += p[c1];
        }
    }

    float ss = v0 * v0 + v1 * v1;
    #pragma unroll
    for (int off = 32; off > 0; off >>= 1) ss += __shfl_down(ss, off);
    __shared__ float sbuf[4];
    if ((tid & 63) == 0) sbuf[tid >> 6] = ss;
    __syncthreads();
    const float total = sbuf[0] + sbuf[1] + sbuf[2] + sbuf[3];
    const float inv = 1.f / fmaxf(sqrtf(total), 1e-12f);

    float* outp = (isV ? Vout : Aout) + (size_t)r * 512;
    outp[c0] = v0 * inv;
    outp[c1] = v1 * inv;
}

// ---------------------------------------------------------------------------
// similarity: S = Anorm . Vnorm^T (64x64 tiles, f32 in, bf16 MFMA),
// epilogue: den[row&255] += sum_col exp(S); diag-family exp -> num[row&255]
// ---------------------------------------------------------------------------
__global__ __launch_bounds__(256) void sim_kernel(
    const float* __restrict__ A, const float* __restrict__ V,
    float* __restrict__ den, float* __restrict__ num)
{
    __shared__ uint4 As[2][256];
    __shared__ uint4 Bs[2][256];

    const int tid = threadIdx.x;
    const int m0 = (blockIdx.x >> 3) * 64;
    const int n0 = (blockIdx.x & 7) * 64;
    const int nsteps = 16;               // K = 512

    const int a_row = tid >> 2, a_kb = tid & 3;
    const int b_col = tid & 63, b_kb = tid >> 6;
    const int a_u = (a_kb * 64 + a_row) ^ (a_kb << 1);
    const int b_u = (b_kb * 64 + b_col) ^ (b_kb << 1);

    const float* abase = A + (size_t)(m0 + a_row) * 512;
    const float* bptr  = V + (size_t)(n0 + b_col) * 512 + b_kb * 8;
    int aoff = a_kb * 8;

    const int lane = tid & 63, wid = tid >> 6;
    const int wrow = (wid >> 1) * 32, wcol = (wid & 1) * 32;
    const int l15 = lane & 15, lk = lane >> 4;

    int ra[2], rb[2];
    #pragma unroll
    for (int m = 0; m < 2; ++m) ra[m] = (lk * 64 + wrow + m * 16 + l15) ^ (lk << 1);
    #pragma unroll
    for (int n = 0; n < 2; ++n) rb[n] = (lk * 64 + wcol + n * 16 + l15) ^ (lk << 1);

    f32x4 acc[2][2];
    #pragma unroll
    for (int m = 0; m < 2; ++m)
        #pragma unroll
        for (int n = 0; n < 2; ++n) acc[m][n] = f32x4{0.f, 0.f, 0.f, 0.f};

    float4 A0 = *(const float4*)(abase + aoff);
    float4 A1 = *(const float4*)(abase + aoff + 4);
    float4 B0 = *(const float4*)bptr;
    float4 B1 = *(const float4*)(bptr + 4);

    for (int ks = 0; ks < nsteps; ++ks) {
        const int cur = ks & 1;
        const bool more = (ks + 1 < nsteps);
        float4 A0n, A1n, B0n, B1n;
        if (more) {
            aoff += 32; bptr += 32;
            A0n = *(const float4*)(abase + aoff);
            A1n = *(const float4*)(abase + aoff + 4);
            B0n = *(const float4*)bptr;
            B1n = *(const float4*)(bptr + 4);
        }
        uint4 pa;
        pa.x = pk2(A0.x, A0.y); pa.y = pk2(A0.z, A0.w);
        pa.z = pk2(A1.x, A1.y); pa.w = pk2(A1.z, A1.w);
        As[cur][a_u] = pa;
        uint4 pb;
        pb.x = pk2(B0.x, B0.y); pb.y = pk2(B0.z, B0.w);
        pb.z = pk2(B1.x, B1.y); pb.w = pk2(B1.z, B1.w);
        Bs[cur][b_u] = pb;
        __syncthreads();

        bf16x8 af[2], bfr[2];
        #pragma unroll
        for (int m = 0; m < 2; ++m) af[m] = __builtin_bit_cast(bf16x8, As[cur][ra[m]]);
        #pragma unroll
        for (int n = 0; n < 2; ++n) bfr[n] = __builtin_bit_cast(bf16x8, Bs[cur][rb[n]]);
        #pragma unroll
        for (int m = 0; m < 2; ++m)
            #pragma unroll
            for (int n = 0; n < 2; ++n)
                acc[m][n] = __builtin_amdgcn_mfma_f32_16x16x32_bf16(af[m], bfr[n], acc[m][n], 0, 0, 0);

        if (more) { A0 = A0n; A1 = A1n; B0 = B0n; B1 = B1n; }
    }

    #pragma unroll
    for (int m = 0; m < 2; ++m) {
        float rs[4] = {0.f, 0.f, 0.f, 0.f};
        #pragma unroll
        for (int n = 0; n < 2; ++n) {
            const int col = n0 + wcol + n * 16 + l15;
            #pragma unroll
            for (int r = 0; r < 4; ++r) {
                const int row = m0 + wrow + m * 16 + lk * 4 + r;
                const float e = __expf(acc[m][n][r]);
                rs[r] += e;
                if (((row - col) & 255) == 0) atomicAdd(num + (row & 255), e);
            }
        }
        #pragma unroll
        for (int r = 0; r < 4; ++r) {
            float v = rs[r];
            v += __shfl_xor(v, 1);
            v += __shfl_xor(v, 2);
            v += __shfl_xor(v, 4);
            v += __shfl_xor(v, 8);
            if (l15 == 0) {
                const int row = m0 + wrow + m * 16 + lk * 4 + r;
                atomicAdd(den + (row & 255), v);
            }
        }
    }
}

// ---------- zero den/num accumulators ----------
__global__ __launch_bounds__(512) void zero_kernel(float* __restrict__ p) {
    p[threadIdx.x] = 0.f;
}

// ---------- a1.a2 and v1.v2 dots -> num += exp(dot) ----------
__global__ __launch_bounds__(256) void dots_kernel(
    const float* __restrict__ A, const float* __restrict__ V,
    float* __restrict__ num)
{
    const int b = blockIdx.x;            // 0..511
    const int i = b & 255;
    const float* X = (b < 256) ? A : V;
    const float* x = X + (size_t)i * 512;
    const float* y = X + (size_t)(i + 256) * 512;
    const int tid = threadIdx.x;
    float d = x[tid] * y[tid] + x[tid + 256] * y[tid + 256];
    #pragma unroll
    for (int off = 32; off > 0; off >>= 1) d += __shfl_down(d, off);
    __shared__ float sbuf[4];
    if ((tid & 63) == 0) sbuf[tid >> 6] = d;
    __syncthreads();
    if (tid == 0) atomicAdd(num + i, __expf(sbuf[0] + sbuf[1] + sbuf[2] + sbuf[3]));
}

// ---------- final: loss = mean(log den - log num) ----------
__global__ __launch_bounds__(256) void final_kernel(
    const float* __restrict__ den, const float* __restrict__ num,
    float* __restrict__ out)
{
    const int tid = threadIdx.x;
    float v = logf(den[tid]) - logf(num[tid]);
    #pragma unroll
    for (int off = 32; off > 0; off >>= 1) v += __shfl_down(v, off);
    __shared__ float sbuf[4];
    if ((tid & 63) == 0) sbuf[tid >> 6] = v;
    __syncthreads();
    if (tid == 0) out[0] = (sbuf[0] + sbuf[1] + sbuf[2] + sbuf[3]) * (1.f / 256.f);
}

// ---------- launch ----------
extern "C" void kernel_launch(void* const* d_in, const int* in_sizes, int n_in,
                              void* d_out, int out_size, void* d_ws, size_t ws_size,
                              hipStream_t stream)
{
    (void)in_sizes; (void)n_in; (void)out_size; (void)ws_size;
    const float* a_1 = (const float*)d_in[0];
    const float* v_1 = (const float*)d_in[1];
    const float* a_2 = (const float*)d_in[2];
    const float* v_2 = (const float*)d_in[3];
    const float* W_a = (const float*)d_in[4];
    const float* W_v = (const float*)d_in[5];
    float* out = (float*)d_out;

    float* cur   = (float*)d_ws;
    float* den   = cur; cur += 256;
    float* num   = cur; cur += 256;
    float* Anorm = cur; cur += 262144;
    float* Vnorm = cur; cur += 262144;
    float* partA = cur; cur += (size_t)ZA * 262144;
    float* partV = cur; cur += (size_t)ZV * 262144;   // ~78 MB total

    zero_kernel<<<1, 512, 0, stream>>>(den);   // zeros den[256]+num[256]

    fgemm<1><<<16 * ZV, 256, 0, stream>>>(v_1, v_2, W_v, partV, 12);
    fgemm<0><<<16 * ZA, 256, 0, stream>>>(a_1, a_2, W_a, partA, 10);

    norm_kernel<<<1024, 256, 0, stream>>>(partA, partV, Anorm, Vnorm, ZV);
    sim_kernel<<<64, 256, 0, stream>>>(Anorm, Vnorm, den, num);
    dots_kernel<<<512, 256, 0, stream>>>(Anorm, Vnorm, num);
    final_kernel<<<1, 256, 0, stream>>>(den, num, out);
}

// Round 11
// 237.568 us; speedup vs baseline: 1.1066x; 1.1066x over previous
//
#include <hip/hip_runtime.h>

typedef __attribute__((ext_vector_type(8))) short bf16x8;   // 8 bf16 (4 VGPRs)
typedef __attribute__((ext_vector_type(4))) float f32x4;
typedef __attribute__((ext_vector_type(2))) float f32x2;

#define ZV 72    // visual split-K: 72 * 12 * 64 = 69120
#define ZA 2     // audio  split-K:  2 * 10 * 64 = 1280

// pack two f32 -> one dword of 2 bf16 (RNE)
__device__ __forceinline__ unsigned int pk2(float a, float b) {
    unsigned int r;
    asm("v_cvt_pk_bf16_f32 %0, %1, %2" : "=v"(r) : "v"(a), "v"(b));
    return r;
}
// pinned loads: issue point fixed, dest regs forced live
#define GL4(d, p, IMM) asm volatile("global_load_dwordx4 %0, %1, off offset:" #IMM : "=&v"(d) : "v"(p))
#define GL2(d, p, IMM) asm volatile("global_load_dwordx2 %0, %1, off offset:" #IMM : "=&v"(d) : "v"(p))

__device__ __forceinline__ void wait_vm24() {
    asm volatile("s_waitcnt vmcnt(24)" ::: "memory");
    __builtin_amdgcn_sched_barrier(0);
}
__device__ __forceinline__ void wait_vm0() {
    asm volatile("s_waitcnt vmcnt(0)" ::: "memory");
    __builtin_amdgcn_sched_barrier(0);
}
__device__ __forceinline__ void barrier_lgkm() {   // no vmcnt drain!
    asm volatile("s_waitcnt lgkmcnt(0)" ::: "memory");
    __builtin_amdgcn_sched_barrier(0);
    __builtin_amdgcn_s_barrier();
    __builtin_amdgcn_sched_barrier(0);
}
__device__ __forceinline__ void barrier_only() {
    __builtin_amdgcn_sched_barrier(0);
    __builtin_amdgcn_s_barrier();
    __builtin_amdgcn_sched_barrier(0);
}

// ---------------------------------------------------------------------------
// Fused GEMM: C[512,512] = A[512,K] * W[K,512], BOTH f32 direct from HBM.
// Tile 128x128, BK=64, 256 thr = 4 waves (2x2 of 64x64), split-K partials.
// LDS: [row][8 units of 8 bf16], unit ^= row&7 (verified ~0-conflict, r10).
// Pipeline: ping-pong register sets; batch t+1 issued before consuming t;
// counted vmcnt(24); raw s_barrier (in-flight loads survive barriers).
// CROP=1: visual (row stride 138240, center crop); CROP=0: audio (1280).
// ---------------------------------------------------------------------------
template<int CROP>
__global__ __launch_bounds__(256, 2) void fgemm(
    const float* __restrict__ s1, const float* __restrict__ s2,
    const float* __restrict__ W, float* __restrict__ part, int ksteps)
{
    __shared__ uint4 As[1024];   // 16 KB
    __shared__ uint4 Bs[1024];   // 16 KB

    const int tid = threadIdx.x;
    const int blk = blockIdx.x;
    const int cpx = gridDim.x >> 3;
    const int lin = (blk & 7) * cpx + (blk >> 3);   // XCD-chunked
    const int z  = lin >> 4;
    const int m0 = ((lin >> 2) & 3) * 128;
    const int n0 = (lin & 3) * 128;                 // n fastest: A-panel shared
    const int k0 = z * ksteps * 64;
    part += (size_t)z * 262144;

    // ---- A staging map: thread -> (row 0..127, k-half 0/1)
    const int a_row  = tid >> 1;
    const int a_half = tid & 1;
    const int grow = m0 + a_row;
    const int ROWSTR = CROP ? 138240 : 1280;
    const float* abase = ((grow < 256) ? s1 + (size_t)grow * ROWSTR
                                       : s2 + (size_t)(grow - 256) * ROWSTR)
                         + a_half * 16;

    // ---- B staging map: thread -> (n-pair, k-oct); 4 persistent pointers
    const int bcol  = 2 * (tid >> 2);      // 0..126 even
    const int b_oct = tid & 3;             // k rows oct*8..+7 per phase
    const float* bb0 = W + (size_t)(k0 + b_oct * 8) * 512 + n0 + bcol;
    const float* bb1 = bb0 + 1024;         // +2 k-rows
    const float* bb2 = bb0 + 2048;
    const float* bb3 = bb0 + 3072;

    // ---- wave / fragment map
    const int wid = tid >> 6, lane = tid & 63;
    const int l15 = lane & 15, lk = lane >> 4;
    const int wm = (wid >> 1) * 64, wn = (wid & 1) * 64;

    int ua[2][4], ub[2][4];
    #pragma unroll
    for (int kh = 0; kh < 2; ++kh) {
        #pragma unroll
        for (int mi = 0; mi < 4; ++mi) {
            const int row = wm + mi * 16 + l15;
            ua[kh][mi] = row * 8 + ((kh * 4 + lk) ^ (row & 7));
        }
        #pragma unroll
        for (int ni = 0; ni < 4; ++ni) {
            const int nn = wn + ni * 16 + l15;
            ub[kh][ni] = nn * 8 + ((kh * 4 + lk) ^ (nn & 7));
        }
    }

    f32x4 acc[4][4];
    #pragma unroll
    for (int mi = 0; mi < 4; ++mi)
        #pragma unroll
        for (int ni = 0; ni < 4; ++ni) acc[mi][ni] = f32x4{0.f, 0.f, 0.f, 0.f};

    // ---- ping-pong staging registers (2 sets)
    f32x4 a0[8], a1[8];        // A: 32 f32 each (2 phases x 16)
    f32x2 b0[16], b1[16];      // B: 16 float2 each (2 phases x 8 rows)

    int kc = k0;               // k of NEXT batch to issue

    auto ISSUE = [&](f32x4* av, f32x2* bv) {
        // A: one pointer, 8 dwordx4 (two 64B chunks, 128B apart)
        int aoffu;
        if (CROP) {
            const int p = kc / 4608;           // uniform; 4608 % 64 == 0
            const int j = kc - p * 4608;
            const int c3 = p % 3, t9 = p / 3;
            aoffu = c3 * 46080 + t9 * 9216 + 4608 + j;
        } else {
            aoffu = kc;
        }
        const float* ap = abase + aoffu;
        GL4(av[0], ap, 0);   GL4(av[1], ap, 16);
        GL4(av[2], ap, 32);  GL4(av[3], ap, 48);
        GL4(av[4], ap, 128); GL4(av[5], ap, 144);
        GL4(av[6], ap, 160); GL4(av[7], ap, 176);
        // B phase 0 (k rows oct*8..+7), then bump +32 rows, phase 1, bump again
        GL2(bv[0],  bb0, 0); GL2(bv[1],  bb0, 2048);
        GL2(bv[2],  bb1, 0); GL2(bv[3],  bb1, 2048);
        GL2(bv[4],  bb2, 0); GL2(bv[5],  bb2, 2048);
        GL2(bv[6],  bb3, 0); GL2(bv[7],  bb3, 2048);
        bb0 += 16384; bb1 += 16384; bb2 += 16384; bb3 += 16384;   // +32 k-rows
        GL2(bv[8],  bb0, 0); GL2(bv[9],  bb0, 2048);
        GL2(bv[10], bb1, 0); GL2(bv[11], bb1, 2048);
        GL2(bv[12], bb2, 0); GL2(bv[13], bb2, 2048);
        GL2(bv[14], bb3, 0); GL2(bv[15], bb3, 2048);
        bb0 += 16384; bb1 += 16384; bb2 += 16384; bb3 += 16384;   // -> next step
        kc += 64;
    };

    auto PACK = [&](const f32x4* av, const f32x2* bv) {
        // A: 4 x b128; unit x = ph*4 + half*2 + c
        #pragma unroll
        for (int q = 0; q < 4; ++q) {             // q = ph*2 + c
            const int x = (q >> 1) * 4 + a_half * 2 + (q & 1);
            const f32x4 f0 = av[2 * q], f1 = av[2 * q + 1];
            uint4 w;
            w.x = pk2(f0.x, f0.y); w.y = pk2(f0.z, f0.w);
            w.z = pk2(f1.x, f1.y); w.w = pk2(f1.z, f1.w);
            As[a_row * 8 + (x ^ (a_row & 7))] = w;
        }
        // B: per phase, vertical k-pairs -> 2 cols x b128
        #pragma unroll
        for (int ph = 0; ph < 2; ++ph) {
            const f32x2* v = bv + ph * 8;
            const int u = ph * 4 + b_oct;
            uint4 p0, p1;
            p0.x = pk2(v[0].x, v[1].x); p0.y = pk2(v[2].x, v[3].x);
            p0.z = pk2(v[4].x, v[5].x); p0.w = pk2(v[6].x, v[7].x);
            p1.x = pk2(v[0].y, v[1].y); p1.y = pk2(v[2].y, v[3].y);
            p1.z = pk2(v[4].y, v[5].y); p1.w = pk2(v[6].y, v[7].y);
            Bs[(bcol)     * 8 + (u ^ ( bcol      & 7))] = p0;
            Bs[(bcol + 1) * 8 + (u ^ ((bcol + 1) & 7))] = p1;
        }
    };

    auto MM = [&]() {
        #pragma unroll
        for (int kh = 0; kh < 2; ++kh) {
            bf16x8 af[4], bfr[4];
            #pragma unroll
            for (int mi = 0; mi < 4; ++mi) af[mi] = __builtin_bit_cast(bf16x8, As[ua[kh][mi]]);
            #pragma unroll
            for (int ni = 0; ni < 4; ++ni) bfr[ni] = __builtin_bit_cast(bf16x8, Bs[ub[kh][ni]]);
            #pragma unroll
            for (int mi = 0; mi < 4; ++mi)
                #pragma unroll
                for (int ni = 0; ni < 4; ++ni)
                    acc[mi][ni] = __builtin_amdgcn_mfma_f32_16x16x32_bf16(af[mi], bfr[ni], acc[mi][ni], 0, 0, 0);
        }
    };

    // ---- prologue: issue batch 0 into set0
    ISSUE(a0, b0);

    // ksteps is even (12 / 10)
    for (int ks = 0; ks < ksteps; ks += 2) {
        // even: prefetch set1 (batch ks+1), consume set0 (batch ks)
        ISSUE(a1, b1);
        wait_vm24();
        PACK(a0, b0);
        barrier_lgkm();
        MM();
        barrier_only();
        // odd: prefetch set0 (batch ks+2), consume set1 (batch ks+1)
        if (ks + 2 < ksteps) { ISSUE(a0, b0); wait_vm24(); }
        else                 { wait_vm0(); }
        PACK(a1, b1);
        barrier_lgkm();
        MM();
        barrier_only();
    }

    // ---- epilogue: fp32 partials. C/D: col = lane&15, row = (lane>>4)*4+r
    #pragma unroll
    for (int mi = 0; mi < 4; ++mi)
        #pragma unroll
        for (int ni = 0; ni < 4; ++ni) {
            const int col = n0 + wn + ni * 16 + l15;
            #pragma unroll
            for (int r = 0; r < 4; ++r) {
                const int row = m0 + wm + mi * 16 + lk * 4 + r;
                part[(size_t)row * 512 + col] = acc[mi][ni][r];
            }
        }
}

// ---------- reduce split-K partials + row L2 normalization ----------
__global__ __launch_bounds__(256) void norm_kernel(
    const float* __restrict__ partA, const float* __restrict__ partV,
    float* __restrict__ Aout, float* __restrict__ Vout, int nzV)
{
    const int row = blockIdx.x;          // 0..1023
    const int tid = threadIdx.x;
    const bool isV = row >= 512;
    const int r = isV ? (row - 512) : row;
    const int c0 = tid, c1 = tid + 256;

    float v0 = 0.f, v1 = 0.f;
    if (isV) {
        for (int zz = 0; zz < nzV; ++zz) {
            const float* p = partV + (size_t)zz * 262144 + (size_t)r * 512;
            v0 += p[c0]; v1 += p[c1];
        }
    } else {
        #pragma unroll
        for (int zz = 0; zz < ZA; ++zz) {
            const float* p = partA + (size_t)zz * 262144 + (size_t)r * 512;
            v0 += p[c0]; v1 += p[c1];
        }
    }

    float ss = v0 * v0 + v1 * v1;
    #pragma unroll
    for (int off = 32; off > 0; off >>= 1) ss += __shfl_down(ss, off);
    __shared__ float sbuf[4];
    if ((tid & 63) == 0) sbuf[tid >> 6] = ss;
    __syncthreads();
    const float total = sbuf[0] + sbuf[1] + sbuf[2] + sbuf[3];
    const float inv = 1.f / fmaxf(sqrtf(total), 1e-12f);

    float* outp = (isV ? Vout : Aout) + (size_t)r * 512;
    outp[c0] = v0 * inv;
    outp[c1] = v1 * inv;
}

// ---------------------------------------------------------------------------
// similarity: S = Anorm . Vnorm^T (64x64 tiles, f32 in, bf16 MFMA),
// epilogue: den[row&255] += sum_col exp(S); diag-family exp -> num[row&255]
// ---------------------------------------------------------------------------
__global__ __launch_bounds__(256) void sim_kernel(
    const float* __restrict__ A, const float* __restrict__ V,
    float* __restrict__ den, float* __restrict__ num)
{
    __shared__ uint4 As[2][256];
    __shared__ uint4 Bs[2][256];

    const int tid = threadIdx.x;
    const int m0 = (blockIdx.x >> 3) * 64;
    const int n0 = (blockIdx.x & 7) * 64;
    const int nsteps = 16;               // K = 512

    const int a_row = tid >> 2, a_kb = tid & 3;
    const int b_col = tid & 63, b_kb = tid >> 6;
    const int a_u = (a_kb * 64 + a_row) ^ (a_kb << 1);
    const int b_u = (b_kb * 64 + b_col) ^ (b_kb << 1);

    const float* abase = A + (size_t)(m0 + a_row) * 512;
    const float* bptr  = V + (size_t)(n0 + b_col) * 512 + b_kb * 8;
    int aoff = a_kb * 8;

    const int lane = tid & 63, wid = tid >> 6;
    const int wrow = (wid >> 1) * 32, wcol = (wid & 1) * 32;
    const int l15 = lane & 15, lk = lane >> 4;

    int ra[2], rb[2];
    #pragma unroll
    for (int m = 0; m < 2; ++m) ra[m] = (lk * 64 + wrow + m * 16 + l15) ^ (lk << 1);
    #pragma unroll
    for (int n = 0; n < 2; ++n) rb[n] = (lk * 64 + wcol + n * 16 + l15) ^ (lk << 1);

    f32x4 acc[2][2];
    #pragma unroll
    for (int m = 0; m < 2; ++m)
        #pragma unroll
        for (int n = 0; n < 2; ++n) acc[m][n] = f32x4{0.f, 0.f, 0.f, 0.f};

    float4 A0 = *(const float4*)(abase + aoff);
    float4 A1 = *(const float4*)(abase + aoff + 4);
    float4 B0 = *(const float4*)bptr;
    float4 B1 = *(const float4*)(bptr + 4);

    for (int ks = 0; ks < nsteps; ++ks) {
        const int cur = ks & 1;
        const bool more = (ks + 1 < nsteps);
        float4 A0n, A1n, B0n, B1n;
        if (more) {
            aoff += 32; bptr += 32;
            A0n = *(const float4*)(abase + aoff);
            A1n = *(const float4*)(abase + aoff + 4);
            B0n = *(const float4*)bptr;
            B1n = *(const float4*)(bptr + 4);
        }
        uint4 pa;
        pa.x = pk2(A0.x, A0.y); pa.y = pk2(A0.z, A0.w);
        pa.z = pk2(A1.x, A1.y); pa.w = pk2(A1.z, A1.w);
        As[cur][a_u] = pa;
        uint4 pb;
        pb.x = pk2(B0.x, B0.y); pb.y = pk2(B0.z, B0.w);
        pb.z = pk2(B1.x, B1.y); pb.w = pk2(B1.z, B1.w);
        Bs[cur][b_u] = pb;
        __syncthreads();

        bf16x8 af[2], bfr[2];
        #pragma unroll
        for (int m = 0; m < 2; ++m) af[m] = __builtin_bit_cast(bf16x8, As[cur][ra[m]]);
        #pragma unroll
        for (int n = 0; n < 2; ++n) bfr[n] = __builtin_bit_cast(bf16x8, Bs[cur][rb[n]]);
        #pragma unroll
        for (int m = 0; m < 2; ++m)
            #pragma unroll
            for (int n = 0; n < 2; ++n)
                acc[m][n] = __builtin_amdgcn_mfma_f32_16x16x32_bf16(af[m], bfr[n], acc[m][n], 0, 0, 0);

        if (more) { A0 = A0n; A1 = A1n; B0 = B0n; B1 = B1n; }
    }

    #pragma unroll
    for (int m = 0; m < 2; ++m) {
        float rs[4] = {0.f, 0.f, 0.f, 0.f};
        #pragma unroll
        for (int n = 0; n < 2; ++n) {
            const int col = n0 + wcol + n * 16 + l15;
            #pragma unroll
            for (int r = 0; r < 4; ++r) {
                const int row = m0 + wrow + m * 16 + lk * 4 + r;
                const float e = __expf(acc[m][n][r]);
                rs[r] += e;
                if (((row - col) & 255) == 0) atomicAdd(num + (row & 255), e);
            }
        }
        #pragma unroll
        for (int r = 0; r < 4; ++r) {
            float v = rs[r];
            v += __shfl_xor(v, 1);
            v += __shfl_xor(v, 2);
            v += __shfl_xor(v, 4);
            v += __shfl_xor(v, 8);
            if (l15 == 0) {
                const int row = m0 + wrow + m * 16 + lk * 4 + r;
                atomicAdd(den + (row & 255), v);
            }
        }
    }
}

// ---------- zero den/num accumulators ----------
__global__ __launch_bounds__(512) void zero_kernel(float* __restrict__ p) {
    p[threadIdx.x] = 0.f;
}

// ---------- a1.a2 and v1.v2 dots -> num += exp(dot) ----------
__global__ __launch_bounds__(256) void dots_kernel(
    const float* __restrict__ A, const float* __restrict__ V,
    float* __restrict__ num)
{
    const int b = blockIdx.x;            // 0..511
    const int i = b & 255;
    const float* X = (b < 256) ? A : V;
    const float* x = X + (size_t)i * 512;
    const float* y = X + (size_t)(i + 256) * 512;
    const int tid = threadIdx.x;
    float d = x[tid] * y[tid] + x[tid + 256] * y[tid + 256];
    #pragma unroll
    for (int off = 32; off > 0; off >>= 1) d += __shfl_down(d, off);
    __shared__ float sbuf[4];
    if ((tid & 63) == 0) sbuf[tid >> 6] = d;
    __syncthreads();
    if (tid == 0) atomicAdd(num + i, __expf(sbuf[0] + sbuf[1] + sbuf[2] + sbuf[3]));
}

// ---------- final: loss = mean(log den - log num) ----------
__global__ __launch_bounds__(256) void final_kernel(
    const float* __restrict__ den, const float* __restrict__ num,
    float* __restrict__ out)
{
    const int tid = threadIdx.x;
    float v = logf(den[tid]) - logf(num[tid]);
    #pragma unroll
    for (int off = 32; off > 0; off >>= 1) v += __shfl_down(v, off);
    __shared__ float sbuf[4];
    if ((tid & 63) == 0) sbuf[tid >> 6] = v;
    __syncthreads();
    if (tid == 0) out[0] = (sbuf[0] + sbuf[1] + sbuf[2] + sbuf[3]) * (1.f / 256.f);
}

// ---------- launch ----------
extern "C" void kernel_launch(void* const* d_in, const int* in_sizes, int n_in,
                              void* d_out, int out_size, void* d_ws, size_t ws_size,
                              hipStream_t stream)
{
    (void)in_sizes; (void)n_in; (void)out_size; (void)ws_size;
    const float* a_1 = (const float*)d_in[0];
    const float* v_1 = (const float*)d_in[1];
    const float* a_2 = (const float*)d_in[2];
    const float* v_2 = (const float*)d_in[3];
    const float* W_a = (const float*)d_in[4];
    const float* W_v = (const float*)d_in[5];
    float* out = (float*)d_out;

    float* cur   = (float*)d_ws;
    float* den   = cur; cur += 256;
    float* num   = cur; cur += 256;
    float* Anorm = cur; cur += 262144;
    float* Vnorm = cur; cur += 262144;
    float* partA = cur; cur += (size_t)ZA * 262144;
    float* partV = cur; cur += (size_t)ZV * 262144;   // ~78 MB total

    zero_kernel<<<1, 512, 0, stream>>>(den);   // zeros den[256]+num[256]

    fgemm<1><<<16 * ZV, 256, 0, stream>>>(v_1, v_2, W_v, partV, 12);
    fgemm<0><<<16 * ZA, 256, 0, stream>>>(a_1, a_2, W_a, partA, 10);

    norm_kernel<<<1024, 256, 0, stream>>>(partA, partV, Anorm, Vnorm, ZV);
    sim_kernel<<<64, 256, 0, stream>>>(Anorm, Vnorm, den, num);
    dots_kernel<<<512, 256, 0, stream>>>(Anorm, Vnorm, num);
    final_kernel<<<1, 256, 0, stream>>>(den, num, out);
}